// Round 9
// baseline (145.073 us; speedup 1.0000x reference)
//
#include <hip/hip_runtime.h>
#include <hip/hip_bf16.h>

// Gemma4AudioRelativePosition — fused bf16-MFMA, round 9.
// out[b,h,n,s,c] = sum_d q[s,d]*k[c,d] + (0<=c-s<=127 ? BD[s,c-s] : 0)
// R9 = R8 with HALF-HEIGHT blocks: each block does a 64-row s-half of one
// (b,h,n) -> 4096 blocks x 256 thr. BDs 32->16KB, LDS total 24KB ->
// 6 blocks/CU = 24 waves/CU (1.5x R5). Request shapes identical to R5/R8.
// Cross-block overlap (the only lever that has moved time) is the target.

typedef __bf16 bf16x8 __attribute__((ext_vector_type(8)));
typedef unsigned short u16x8 __attribute__((ext_vector_type(8)));
typedef unsigned int u32x4 __attribute__((ext_vector_type(4)));
typedef float f32x4 __attribute__((ext_vector_type(4)));

__device__ __forceinline__ unsigned short f2bf(float f) {
    unsigned u = __float_as_uint(f);
    u = (u + 0x7FFFu + ((u >> 16) & 1u)) >> 16;   // RNE
    return (unsigned short)u;
}
__device__ __forceinline__ float bf2f(unsigned short s) {
    return __uint_as_float(((unsigned)s) << 16);
}
// truncation pack: two fp32 -> packed 2x bf16
__device__ __forceinline__ unsigned pk2(float a, float b) {
    return (__float_as_uint(a) >> 16) | (__float_as_uint(b) & 0xFFFF0000u);
}

// Raw barrier: order LDS writes (lgkmcnt) but leave global loads in flight.
__device__ __forceinline__ void barrier_no_vm_drain() {
    asm volatile("s_waitcnt lgkmcnt(0)" ::: "memory");
    __builtin_amdgcn_s_barrier();
}

// ---------------- kernel 1: proj = sin_emb @ W_pos^T  (bf16 out) ----------------
// grid 1024 = (p 0..127) x (jq 0..7); block computes proj[p, jq*64 .. jq*64+64)
__global__ __launch_bounds__(256) void proj_kernel(const float* __restrict__ W,
                                                   unsigned short* __restrict__ projw) {
    __shared__ float se[512];
    int bid = blockIdx.x;
    int p  = bid >> 3;      // 0..127
    int jq = bid & 7;       // 0..7
    int t = threadIdx.x;    // 0..255
    const float LOGINC = (float)(9.210340371976184 / 255.0);  // ln(1e4)/255
    float pos = (float)(127 - p);
    float inv = expf(-LOGINC * (float)t);
    float ang = pos * inv;
    se[t]       = sinf(ang);
    se[t + 256] = cosf(ang);
    __syncthreads();
    int j  = jq * 64 + (t >> 2);
    int tq = t & 3;
    const float4* wr = (const float4*)(W + (size_t)j * 512 + tq * 128);
    const float4* sr = (const float4*)(se + tq * 128);
    float a = 0.f;
#pragma unroll
    for (int i = 0; i < 32; ++i) {
        float4 wv = wr[i];
        float4 sv = sr[i];
        a += sv.x * wv.x + sv.y * wv.y + sv.z * wv.z + sv.w * wv.w;
    }
    a += __shfl_xor(a, 1);
    a += __shfl_xor(a, 2);
    if (tq == 0) projw[p * 512 + j] = f2bf(a);
}

// ---------------- kernel 2: fused AC + skewed BD (64-row half-blocks) ----------
__global__ __launch_bounds__(256, 6) void fused_kernel(const float* __restrict__ Q,
                                                       const float* __restrict__ Kg,
                                                       const unsigned short* __restrict__ projw,
                                                       float* __restrict__ out) {
    __shared__ unsigned short BDs[64 * 128];      // BD[s_loc][(s_g+p)&127] bf16 swz (16KB)
    __shared__ unsigned short Klds[2][32 * 64];   // double-buffered 32-row chunks (8KB)

    // XCD-aware remap: all 16 (h,sub) siblings of a (b,n) adjacent on one XCD.
    int bid = blockIdx.x;
    int wid = (bid & 7) * 512 + (bid >> 3);   // 4096 blocks = 8 XCD x 512
    int sub = wid & 1;                        // s-half: rows [sub*64, sub*64+64)
    int h = (wid >> 1) & 7;
    int n = (wid >> 4) & 63;
    int b = wid >> 10;

    const float* qbase = Q  + ((size_t)((b * 64 + n) * 128 + sub * 64)) * 512 + h * 64;
    const float* kbase = Kg + ((size_t)(b * 64 + n) * 256) * 512 + h * 64;

    int tid = threadIdx.x;
    int w  = tid >> 6;     // wave 0..3 -> s-tile [16w, 16w+16) within the half
    int l  = tid & 63;
    int lo = l & 15;
    int hi = l >> 4;
    int rq = l >> 4;       // 0..3: row-in-quad for K staging
    int cq = l & 15;       // 0..15: float4 col slot (4 rows x 256B per instr)

    int s_loc = w * 16 + lo;          // 0..63
    int s_g   = sub * 64 + s_loc;     // global s

    // ---- Q loads FIRST (their vmcnt wait won't include the K queue)
    float4 qv[4];
    {
        const float* ar = qbase + (size_t)s_loc * 512;
        qv[0] = *(const float4*)(ar + hi * 8);
        qv[1] = *(const float4*)(ar + hi * 8 + 4);
        qv[2] = *(const float4*)(ar + 32 + hi * 8);
        qv[3] = *(const float4*)(ar + 32 + hi * 8 + 4);
    }

    // ---- K prefetch, 2 chunks deep (chunk = 32 rows; 2 float4/thread each)
    float4 kpre[2][2];
#pragma unroll
    for (int it = 0; it < 2; ++it) {
        int row = w * 8 + it * 4 + rq;
        kpre[0][it] = *(const float4*)(kbase + (size_t)(0 * 32 + row) * 512 + cq * 4);
    }
#pragma unroll
    for (int it = 0; it < 2; ++it) {
        int row = w * 8 + it * 4 + rq;
        kpre[1][it] = *(const float4*)(kbase + (size_t)(1 * 32 + row) * 512 + cq * 4);
    }

    // ---- pack A-fragment (waits only on Q loads)
    bf16x8 afrag[2];
#pragma unroll
    for (int kk = 0; kk < 2; ++kk) {
        float4 va = qv[kk * 2], vb = qv[kk * 2 + 1];
        u16x8 u;
        u[0] = f2bf(va.x); u[1] = f2bf(va.y); u[2] = f2bf(va.z); u[3] = f2bf(va.w);
        u[4] = f2bf(vb.x); u[5] = f2bf(vb.y); u[6] = f2bf(vb.z); u[7] = f2bf(vb.w);
        afrag[kk] = __builtin_bit_cast(bf16x8, u);
    }

    // ---- Phase 1: BD = proj @ A^T (swapped) -> col(lo)=s, row(hi*4+jr)=p.
    // Skew-store bf16 to BDs (row s_loc, col (s_g+p)&127). Same wave writes &
    // reads its own rows. Hides the 2-deep K prefetch latency.
    const unsigned short* pbase = projw + h * 64;
#pragma unroll 2
    for (int pj = 0; pj < 8; ++pj) {
        int prow = pj * 16 + lo;
        const unsigned short* pr = pbase + (size_t)prow * 512;
        bf16x8 pf0 = *(const bf16x8*)(pr + hi * 8);
        bf16x8 pf1 = *(const bf16x8*)(pr + 32 + hi * 8);
        f32x4 acc = {0.f, 0.f, 0.f, 0.f};
        acc = __builtin_amdgcn_mfma_f32_16x16x32_bf16(pf0, afrag[0], acc, 0, 0, 0);
        acc = __builtin_amdgcn_mfma_f32_16x16x32_bf16(pf1, afrag[1], acc, 0, 0, 0);
        int pb = pj * 16 + hi * 4;
#pragma unroll
        for (int jr = 0; jr < 4; ++jr) {
            int cw = (s_g + pb + jr) & 127;   // band 128 wide -> mod-128 bijection
            BDs[s_loc * 128 + (cw ^ ((s_loc & 7) << 3))] = f2bf(acc[jr]);
        }
    }

    // ---- Main loop: 8 chunks x 32 K-rows, double-buffered, ONE raw barrier/chunk.
    size_t obase = ((size_t)((b * 8 + h) * 64 + n)) * (128 * 256) + (size_t)sub * 64 * 256;
    int stile_g = sub * 4 + w;   // global 16-row s-tile index of this wave

#pragma unroll
    for (int ch = 0; ch < 8; ++ch) {
        const int buf = ch & 1;
        // stage buf from its prefetch set
#pragma unroll
        for (int it = 0; it < 2; ++it) {
            int row = w * 8 + it * 4 + rq;        // chunk-local row 0..31
            float4 v = kpre[buf][it];
            uint2 pk;
            pk.x = pk2(v.x, v.y);
            pk.y = pk2(v.z, v.w);
            *reinterpret_cast<uint2*>(&Klds[buf][row * 64 + ((cq * 4) ^ ((row & 7) << 3))]) = pk;
        }
        // refill this set for chunk ch+2 (stays in flight across the barrier)
        if (ch < 6) {
#pragma unroll
            for (int it = 0; it < 2; ++it) {
                int row = w * 8 + it * 4 + rq;
                kpre[buf][it] =
                    *(const float4*)(kbase + (size_t)((ch + 2) * 32 + row) * 512 + cq * 4);
            }
        }
        barrier_no_vm_drain();   // lgkmcnt(0) + s_barrier, NO vmcnt drain

        // compute the 2 cj tiles of this chunk against this wave's s-tile
#pragma unroll
        for (int cjl = 0; cjl < 2; ++cjl) {
            int cj  = ch * 2 + cjl;
            int krl = cjl * 16 + lo;              // chunk-local K row
            bf16x8 kf0 = *(const bf16x8*)&Klds[buf][krl * 64 + ((hi * 8)      ^ ((krl & 7) << 3))];
            bf16x8 kf1 = *(const bf16x8*)&Klds[buf][krl * 64 + ((32 + hi * 8) ^ ((krl & 7) << 3))];
            f32x4 acc = {0.f, 0.f, 0.f, 0.f};
            acc = __builtin_amdgcn_mfma_f32_16x16x32_bf16(kf0, afrag[0], acc, 0, 0, 0);
            acc = __builtin_amdgcn_mfma_f32_16x16x32_bf16(kf1, afrag[1], acc, 0, 0, 0);
            int cb = cj * 16 + hi * 4;
            if (cj >= stile_g && cj <= stile_g + 8) {   // band-active (uniform/wave)
                uint2 pk = *(const uint2*)&BDs[s_loc * 128 + ((cb & 127) ^ ((s_loc & 7) << 3))];
                unsigned short v0 = (unsigned short)(pk.x & 0xffffu);
                unsigned short v1 = (unsigned short)(pk.x >> 16);
                unsigned short v2 = (unsigned short)(pk.y & 0xffffu);
                unsigned short v3 = (unsigned short)(pk.y >> 16);
                if ((unsigned)(cb + 0 - s_g) < 128u) acc[0] += bf2f(v0);
                if ((unsigned)(cb + 1 - s_g) < 128u) acc[1] += bf2f(v1);
                if ((unsigned)(cb + 2 - s_g) < 128u) acc[2] += bf2f(v2);
                if ((unsigned)(cb + 3 - s_g) < 128u) acc[3] += bf2f(v3);
            }
            *reinterpret_cast<float4*>(&out[obase + (size_t)s_loc * 256 + cb]) =
                *reinterpret_cast<float4*>(&acc);
        }
    }
}

extern "C" void kernel_launch(void* const* d_in, const int* in_sizes, int n_in,
                              void* d_out, int out_size, void* d_ws, size_t ws_size,
                              hipStream_t stream) {
    const float* Q  = (const float*)d_in[0];
    const float* Kg = (const float*)d_in[1];
    const float* W  = (const float*)d_in[2];
    float* out = (float*)d_out;
    unsigned short* projw = (unsigned short*)d_ws;   // 128*512 bf16 = 128 KB

    hipLaunchKernelGGL(proj_kernel, dim3(1024), dim3(256), 0, stream, W, projw);
    hipLaunchKernelGGL(fused_kernel, dim3(4096), dim3(256), 0, stream, Q, Kg, projw, out);
}

// Round 10
// 117.770 us; speedup vs baseline: 1.2318x; 1.2318x over previous
//
#include <hip/hip_runtime.h>
#include <hip/hip_bf16.h>

// Gemma4AudioRelativePosition — fused bf16-MFMA, round 10.
// out[b,h,n,s,c] = sum_d q[s,d]*k[c,d] + (0<=c-s<=127 ? BD[s,c-s] : 0)
// R10 = EXACT R5 structure (best measured, 131us) + ONE change: output stores
// are nontemporal (__builtin_nontemporal_store -> 'nt' stores). The 268MB
// write stream no longer write-allocates in L2/L3, so L3 keeps the (L3-
// resident) Q/K/proj inputs instead of being thrashed by output lines.

typedef __bf16 bf16x8 __attribute__((ext_vector_type(8)));
typedef unsigned short u16x8 __attribute__((ext_vector_type(8)));
typedef unsigned int u32x4 __attribute__((ext_vector_type(4)));
typedef float f32x4 __attribute__((ext_vector_type(4)));

__device__ __forceinline__ unsigned short f2bf(float f) {
    unsigned u = __float_as_uint(f);
    u = (u + 0x7FFFu + ((u >> 16) & 1u)) >> 16;   // RNE
    return (unsigned short)u;
}
__device__ __forceinline__ float bf2f(unsigned short s) {
    return __uint_as_float(((unsigned)s) << 16);
}
// truncation pack: two fp32 -> packed 2x bf16
__device__ __forceinline__ unsigned pk2(float a, float b) {
    return (__float_as_uint(a) >> 16) | (__float_as_uint(b) & 0xFFFF0000u);
}

// ---------------- kernel 1: proj = sin_emb @ W_pos^T  (bf16 out) ----------------
// grid 1024 = (p 0..127) x (jq 0..7); block computes proj[p, jq*64 .. jq*64+64)
__global__ __launch_bounds__(256) void proj_kernel(const float* __restrict__ W,
                                                   unsigned short* __restrict__ projw) {
    __shared__ float se[512];
    int bid = blockIdx.x;
    int p  = bid >> 3;      // 0..127
    int jq = bid & 7;       // 0..7
    int t = threadIdx.x;    // 0..255
    const float LOGINC = (float)(9.210340371976184 / 255.0);  // ln(1e4)/255
    float pos = (float)(127 - p);
    float inv = expf(-LOGINC * (float)t);
    float ang = pos * inv;
    se[t]       = sinf(ang);
    se[t + 256] = cosf(ang);
    __syncthreads();
    int j  = jq * 64 + (t >> 2);
    int tq = t & 3;
    const float4* wr = (const float4*)(W + (size_t)j * 512 + tq * 128);
    const float4* sr = (const float4*)(se + tq * 128);
    float a = 0.f;
#pragma unroll
    for (int i = 0; i < 32; ++i) {
        float4 wv = wr[i];
        float4 sv = sr[i];
        a += sv.x * wv.x + sv.y * wv.y + sv.z * wv.z + sv.w * wv.w;
    }
    a += __shfl_xor(a, 1);
    a += __shfl_xor(a, 2);
    if (tq == 0) projw[p * 512 + j] = f2bf(a);
}

// ---------------- kernel 2: fused AC + skewed BD ----------------
__global__ __launch_bounds__(256, 4) void fused_kernel(const float* __restrict__ Q,
                                                       const float* __restrict__ Kg,
                                                       const unsigned short* __restrict__ projw,
                                                       float* __restrict__ out) {
    __shared__ unsigned short BDs[128 * 128];   // BD[s][(s+p)&127], bf16, swizzled (32KB)
    __shared__ unsigned short Klds[64 * 64];    // one 64-row K chunk, bf16, swizzled (8KB)

    // XCD-aware remap: h fastest within an XCD's range.
    int bid = blockIdx.x;
    int wid = (bid & 7) * 256 + (bid >> 3);   // 2048 blocks = 8 XCD x 256
    int h = wid & 7;
    int n = (wid >> 3) & 63;
    int b = wid >> 9;

    const float* qbase = Q  + ((size_t)(b * 64 + n) * 128) * 512 + h * 64;
    const float* kbase = Kg + ((size_t)(b * 64 + n) * 256) * 512 + h * 64;

    int tid = threadIdx.x;
    int w  = tid >> 6;     // wave 0..3 -> s-stripe [32w, 32w+32)
    int l  = tid & 63;
    int lo = l & 15;
    int hi = l >> 4;
    int rq = l >> 4;       // 0..3: row-in-quad for staging
    int cq = l & 15;       // 0..15: float4 col slot for staging (full-row pattern)

    // ---- T14: issue K chunk-0 prefetch FIRST (4 rows x 256B contiguous / instr)
    float4 kpre[4];
#pragma unroll
    for (int it = 0; it < 4; ++it) {
        int row = w * 16 + it * 4 + rq;     // chunk-local row 0..63
        kpre[it] = *(const float4*)(kbase + (size_t)row * 512 + cq * 4);
    }

    // ---- A-fragments: global fp32 -> reg bf16 (each q element read exactly once)
    bf16x8 afrag[2][2];
#pragma unroll
    for (int i2 = 0; i2 < 2; ++i2) {
        int row = w * 32 + i2 * 16 + lo;
        const float* ar = qbase + (size_t)row * 512;
#pragma unroll
        for (int kk = 0; kk < 2; ++kk) {
            float4 va = *(const float4*)(ar + kk * 32 + hi * 8);
            float4 vb = *(const float4*)(ar + kk * 32 + hi * 8 + 4);
            u16x8 u;
            u[0] = f2bf(va.x); u[1] = f2bf(va.y); u[2] = f2bf(va.z); u[3] = f2bf(va.w);
            u[4] = f2bf(vb.x); u[5] = f2bf(vb.y); u[6] = f2bf(vb.z); u[7] = f2bf(vb.w);
            afrag[i2][kk] = __builtin_bit_cast(bf16x8, u);
        }
    }

    // ---- Phase 1: BD = proj @ A^T (swapped operands) -> D: col(lo)=s, row(hi,jr)=p
    // Skew-store bf16 to BDs. Same wave writes & reads its own s rows -> no barrier.
    const unsigned short* pbase = projw + h * 64;
#pragma unroll 2
    for (int pj = 0; pj < 8; ++pj) {
        int prow = pj * 16 + lo;
        const unsigned short* pr = pbase + (size_t)prow * 512;
        bf16x8 pf0 = *(const bf16x8*)(pr + hi * 8);
        bf16x8 pf1 = *(const bf16x8*)(pr + 32 + hi * 8);
#pragma unroll
        for (int i2 = 0; i2 < 2; ++i2) {
            f32x4 acc = {0.f, 0.f, 0.f, 0.f};
            acc = __builtin_amdgcn_mfma_f32_16x16x32_bf16(pf0, afrag[i2][0], acc, 0, 0, 0);
            acc = __builtin_amdgcn_mfma_f32_16x16x32_bf16(pf1, afrag[i2][1], acc, 0, 0, 0);
            int s  = w * 32 + i2 * 16 + lo;
            int pb = pj * 16 + hi * 4;
#pragma unroll
            for (int jr = 0; jr < 4; ++jr) {
                int cw = (s + pb + jr) & 127;     // band 128 wide -> mod-128 bijection
                BDs[s * 128 + (cw ^ ((s & 7) << 3))] = f2bf(acc[jr]);
            }
        }
    }

    // ---- Main loop: 4 K-chunks of 64 rows. Stage (regs->LDS), prefetch next,
    // barrier, compute 4 cj tiles, barrier.
    size_t obase = ((size_t)((b * 8 + h) * 64 + n)) * (128 * 256);

    for (int ch = 0; ch < 4; ++ch) {
        if (ch) __syncthreads();   // prev chunk's reads done before overwrite

        // pack prefetched chunk into LDS (swizzled)
#pragma unroll
        for (int it = 0; it < 4; ++it) {
            int row = w * 16 + it * 4 + rq;     // chunk-local row
            float4 v = kpre[it];
            uint2 pk;
            pk.x = pk2(v.x, v.y);
            pk.y = pk2(v.z, v.w);
            int col = cq * 4;
            *reinterpret_cast<uint2*>(&Klds[row * 64 + (col ^ ((row & 7) << 3))]) = pk;
        }

        // issue next chunk's prefetch (T14: in flight across compute below)
        if (ch < 3) {
#pragma unroll
            for (int it = 0; it < 4; ++it) {
                int row = w * 16 + it * 4 + rq;
                kpre[it] = *(const float4*)(kbase + (size_t)((ch + 1) * 64 + row) * 512 + cq * 4);
            }
        }

        __syncthreads();           // staging visible to all waves

        // compute cj tiles of this chunk
#pragma unroll
        for (int cjl = 0; cjl < 4; ++cjl) {
            int cj = ch * 4 + cjl;
            int krl = cjl * 16 + lo;    // chunk-local K row
            bf16x8 kf0 = *(const bf16x8*)&Klds[krl * 64 + ((hi * 8)      ^ ((krl & 7) << 3))];
            bf16x8 kf1 = *(const bf16x8*)&Klds[krl * 64 + ((32 + hi * 8) ^ ((krl & 7) << 3))];
#pragma unroll
            for (int i2 = 0; i2 < 2; ++i2) {
                int stile = 2 * w + i2;
                f32x4 acc = {0.f, 0.f, 0.f, 0.f};
                acc = __builtin_amdgcn_mfma_f32_16x16x32_bf16(kf0, afrag[i2][0], acc, 0, 0, 0);
                acc = __builtin_amdgcn_mfma_f32_16x16x32_bf16(kf1, afrag[i2][1], acc, 0, 0, 0);
                int s  = stile * 16 + lo;
                int cb = cj * 16 + hi * 4;
                if (cj >= stile && cj <= stile + 8) {   // band-active (uniform/wave)
                    uint2 pk = *(const uint2*)&BDs[s * 128 + ((cb & 127) ^ ((s & 7) << 3))];
                    unsigned short v0 = (unsigned short)(pk.x & 0xffffu);
                    unsigned short v1 = (unsigned short)(pk.x >> 16);
                    unsigned short v2 = (unsigned short)(pk.y & 0xffffu);
                    unsigned short v3 = (unsigned short)(pk.y >> 16);
                    if ((unsigned)(cb + 0 - s) < 128u) acc[0] += bf2f(v0);
                    if ((unsigned)(cb + 1 - s) < 128u) acc[1] += bf2f(v1);
                    if ((unsigned)(cb + 2 - s) < 128u) acc[2] += bf2f(v2);
                    if ((unsigned)(cb + 3 - s) < 128u) acc[3] += bf2f(v3);
                }
                // Nontemporal: stream the output past L2/L3 (write-once data).
                __builtin_nontemporal_store(
                    *reinterpret_cast<f32x4*>(&acc),
                    reinterpret_cast<f32x4*>(&out[obase + (size_t)s * 256 + cb]));
            }
        }
    }
}

extern "C" void kernel_launch(void* const* d_in, const int* in_sizes, int n_in,
                              void* d_out, int out_size, void* d_ws, size_t ws_size,
                              hipStream_t stream) {
    const float* Q  = (const float*)d_in[0];
    const float* Kg = (const float*)d_in[1];
    const float* W  = (const float*)d_in[2];
    float* out = (float*)d_out;
    unsigned short* projw = (unsigned short*)d_ws;   // 128*512 bf16 = 128 KB

    hipLaunchKernelGGL(proj_kernel, dim3(1024), dim3(256), 0, stream, W, projw);
    hipLaunchKernelGGL(fused_kernel, dim3(2048), dim3(256), 0, stream, Q, Kg, projw, out);
}